// Round 1
// baseline (3045.779 us; speedup 1.0000x reference)
//
#include <hip/hip_runtime.h>

#define N_NODES 150018
#define DIMS 64
#define NELEM (N_NODES * DIMS)          // 9,601,152 floats
#define NVEC4 (NELEM / 4)               // 2,400,288 float4

// out[i] = src[i]  (vectorized copy: init accumulator with embedding)
__global__ void copy_k(const float4* __restrict__ src, float4* __restrict__ dst, int n4) {
    int i = blockIdx.x * blockDim.x + threadIdx.x;
    if (i < n4) dst[i] = src[i];
}

// acc[i] += x[i]
__global__ void add_k(float4* __restrict__ acc, const float4* __restrict__ x, int n4) {
    int i = blockIdx.x * blockDim.x + threadIdx.x;
    if (i < n4) {
        float4 a = acc[i], b = x[i];
        a.x += b.x; a.y += b.y; a.z += b.z; a.w += b.w;
        acc[i] = a;
    }
}

// acc[i] *= 0.25f
__global__ void scale_k(float4* __restrict__ acc, int n4) {
    int i = blockIdx.x * blockDim.x + threadIdx.x;
    if (i < n4) {
        float4 a = acc[i];
        a.x *= 0.25f; a.y *= 0.25f; a.z *= 0.25f; a.w *= 0.25f;
        acc[i] = a;
    }
}

// One wave (64 lanes) per edge, grid-stride over edges.
// lane l: out[rows[e]*64 + l] += vals[e] * x[cols[e]*64 + l]
__global__ void spmm_atomic_k(const float* __restrict__ x,
                              const float* __restrict__ vals,
                              const int* __restrict__ rows,
                              const int* __restrict__ cols,
                              float* __restrict__ out,
                              int n_edges) {
    const int lane   = threadIdx.x & 63;
    const int wpb    = blockDim.x >> 6;                    // waves per block
    int wave         = blockIdx.x * wpb + (threadIdx.x >> 6);
    const int nwaves = gridDim.x * wpb;
    for (int e = wave; e < n_edges; e += nwaves) {
        const int   c = cols[e];
        const int   r = rows[e];
        const float v = vals[e];
        const float g = x[(c << 6) + lane] * v;
        atomicAdd(out + (r << 6) + lane, g);
    }
}

extern "C" void kernel_launch(void* const* d_in, const int* in_sizes, int n_in,
                              void* d_out, int out_size, void* d_ws, size_t ws_size,
                              hipStream_t stream) {
    const float* emb  = (const float*)d_in[0];
    const float* vals = (const float*)d_in[1];
    const int*   rows = (const int*)d_in[2];
    const int*   cols = (const int*)d_in[3];
    float*       out  = (float*)d_out;
    const int n_edges = in_sizes[1];

    const size_t node_bytes = (size_t)NELEM * sizeof(float);
    float* bufA = (float*)d_ws;
    float* bufB = bufA + (size_t)NELEM;

    const int EW_BLK = 256;
    const int ew_grid = (NVEC4 + EW_BLK - 1) / EW_BLK;

    const int SP_BLK  = 256;   // 4 waves/block
    const int SP_GRID = 2048;  // 8192 waves resident, grid-stride

    // acc (d_out) = embedding
    copy_k<<<ew_grid, EW_BLK, 0, stream>>>((const float4*)emb, (float4*)out, NVEC4);

    // Layer 1: emb -> A ; acc += A
    hipMemsetAsync(bufA, 0, node_bytes, stream);
    spmm_atomic_k<<<SP_GRID, SP_BLK, 0, stream>>>(emb, vals, rows, cols, bufA, n_edges);
    add_k<<<ew_grid, EW_BLK, 0, stream>>>((float4*)out, (const float4*)bufA, NVEC4);

    // Layer 2: A -> B ; acc += B
    hipMemsetAsync(bufB, 0, node_bytes, stream);
    spmm_atomic_k<<<SP_GRID, SP_BLK, 0, stream>>>(bufA, vals, rows, cols, bufB, n_edges);
    add_k<<<ew_grid, EW_BLK, 0, stream>>>((float4*)out, (const float4*)bufB, NVEC4);

    // Layer 3: B -> scatter directly into acc (d_out already holds emb+L1+L2)
    spmm_atomic_k<<<SP_GRID, SP_BLK, 0, stream>>>(bufB, vals, rows, cols, out, n_edges);

    // acc *= 0.25
    scale_k<<<ew_grid, EW_BLK, 0, stream>>>((float4*)out, NVEC4);
}

// Round 2
// 1329.083 us; speedup vs baseline: 2.2916x; 2.2916x over previous
//
#include <hip/hip_runtime.h>

#define N_NODES 150018
#define DIMS 64
#define NELEM (N_NODES * DIMS)            // 9,601,152 floats
#define SCAN_BLK 256
#define N_SCAN_BLOCKS ((N_NODES + SCAN_BLK - 1) / SCAN_BLK)   // 587

// ---- CSR build ----------------------------------------------------------

__global__ void hist_k(const int* __restrict__ rows, int* __restrict__ counts, int n) {
    int i = blockIdx.x * blockDim.x + threadIdx.x;
    if (i < n) atomicAdd(&counts[rows[i]], 1);
}

// per-block exclusive scan; block totals to bsum
__global__ void scan_block_k(const int* __restrict__ counts, int* __restrict__ ex,
                             int* __restrict__ bsum, int n) {
    __shared__ int s[SCAN_BLK];
    int i = blockIdx.x * SCAN_BLK + threadIdx.x;
    int v = (i < n) ? counts[i] : 0;
    s[threadIdx.x] = v;
    __syncthreads();
    for (int off = 1; off < SCAN_BLK; off <<= 1) {
        int t = (threadIdx.x >= off) ? s[threadIdx.x - off] : 0;
        __syncthreads();
        s[threadIdx.x] += t;
        __syncthreads();
    }
    if (i < n) ex[i] = s[threadIdx.x] - v;          // exclusive within block
    if (threadIdx.x == SCAN_BLK - 1) bsum[blockIdx.x] = s[SCAN_BLK - 1];
}

// single-block exclusive scan of the 587 block sums
__global__ void scan_sums_k(int* __restrict__ bsum, int nb) {
    __shared__ int s[1024];
    int v = (threadIdx.x < nb) ? bsum[threadIdx.x] : 0;
    s[threadIdx.x] = v;
    __syncthreads();
    for (int off = 1; off < 1024; off <<= 1) {
        int t = (threadIdx.x >= off) ? s[threadIdx.x - off] : 0;
        __syncthreads();
        s[threadIdx.x] += t;
        __syncthreads();
    }
    if (threadIdx.x < nb) bsum[threadIdx.x] = s[threadIdx.x] - v;  // exclusive
}

__global__ void scan_add_k(const int* __restrict__ ex, const int* __restrict__ bsum,
                           int* __restrict__ offs, int* __restrict__ cursor,
                           int n, int n_edges) {
    int i = blockIdx.x * SCAN_BLK + threadIdx.x;
    if (i < n) {
        int o = ex[i] + bsum[blockIdx.x];
        offs[i] = o;
        cursor[i] = o;
    }
    if (i == 0) offs[n] = n_edges;
}

__global__ void scatter_k(const int* __restrict__ rows, const int* __restrict__ cols,
                          const float* __restrict__ vals, int* __restrict__ cursor,
                          int2* __restrict__ edges, int n) {
    int i = blockIdx.x * blockDim.x + threadIdx.x;
    if (i < n) {
        int r = rows[i];
        int pos = atomicAdd(&cursor[r], 1);
        edges[pos] = make_int2(cols[i], __float_as_int(vals[i]));
    }
}

// ---- fused CSR SpMM: one wave per row -----------------------------------
// res[row] = sum_e val*x[col]; buf_out[row]=res (if non-null);
// acc_out[row] = (acc_in[row] + res) * scale
__global__ void spmm_csr_k(const float* __restrict__ x,
                           const int2* __restrict__ edges,
                           const int* __restrict__ offs,
                           const float* __restrict__ acc_in,
                           float* __restrict__ buf_out,
                           float* __restrict__ acc_out,
                           float scale, int n_rows) {
    int gid  = blockIdx.x * blockDim.x + threadIdx.x;
    int row  = gid >> 6;
    int lane = threadIdx.x & 63;
    if (row >= n_rows) return;
    int beg = offs[row], end = offs[row + 1];
    float a0 = 0.f, a1 = 0.f;
    int e = beg;
    for (; e + 2 <= end; e += 2) {
        int2 e0 = edges[e], e1 = edges[e + 1];
        a0 = fmaf(__int_as_float(e0.y), x[(e0.x << 6) + lane], a0);
        a1 = fmaf(__int_as_float(e1.y), x[(e1.x << 6) + lane], a1);
    }
    if (e < end) {
        int2 e0 = edges[e];
        a0 = fmaf(__int_as_float(e0.y), x[(e0.x << 6) + lane], a0);
    }
    float res = a0 + a1;
    int o = (row << 6) + lane;
    if (buf_out) buf_out[o] = res;
    acc_out[o] = (acc_in[o] + res) * scale;
}

// ---- launch -------------------------------------------------------------

extern "C" void kernel_launch(void* const* d_in, const int* in_sizes, int n_in,
                              void* d_out, int out_size, void* d_ws, size_t ws_size,
                              hipStream_t stream) {
    const float* emb  = (const float*)d_in[0];
    const float* vals = (const float*)d_in[1];
    const int*   rows = (const int*)d_in[2];
    const int*   cols = (const int*)d_in[3];
    float*       out  = (float*)d_out;
    const int n_edges = in_sizes[1];

    // workspace layout
    char* w = (char*)d_ws;
    float* bufA  = (float*)w;  w += (size_t)NELEM * 4;
    float* bufB  = (float*)w;  w += (size_t)NELEM * 4;
    int2*  edges = (int2*)w;   w += (size_t)n_edges * 8;
    int* counts  = (int*)w;    w += (size_t)N_NODES * 4;
    int* ex      = (int*)w;    w += (size_t)N_NODES * 4;
    int* offs    = (int*)w;    w += (size_t)(N_NODES + 1) * 4;
    int* cursor  = (int*)w;    w += (size_t)N_NODES * 4;
    int* bsum    = (int*)w;

    const int eg = (n_edges + 255) / 256;

    // CSR build
    hipMemsetAsync(counts, 0, (size_t)N_NODES * 4, stream);
    hist_k<<<eg, 256, 0, stream>>>(rows, counts, n_edges);
    scan_block_k<<<N_SCAN_BLOCKS, SCAN_BLK, 0, stream>>>(counts, ex, bsum, N_NODES);
    scan_sums_k<<<1, 1024, 0, stream>>>(bsum, N_SCAN_BLOCKS);
    scan_add_k<<<N_SCAN_BLOCKS, SCAN_BLK, 0, stream>>>(ex, bsum, offs, cursor, N_NODES, n_edges);
    scatter_k<<<eg, 256, 0, stream>>>(rows, cols, vals, cursor, edges, n_edges);

    // fused SpMM layers: wave per row, 4 waves/block
    const int SP_BLK  = 256;
    const int sp_grid = (N_NODES + 3) / 4;

    // L1: x=emb, acc=emb+r1, bufA=r1
    spmm_csr_k<<<sp_grid, SP_BLK, 0, stream>>>(emb, edges, offs, emb, bufA, out, 1.0f, N_NODES);
    // L2: x=bufA, acc+=r2, bufB=r2
    spmm_csr_k<<<sp_grid, SP_BLK, 0, stream>>>(bufA, edges, offs, out, bufB, out, 1.0f, N_NODES);
    // L3: x=bufB, out=(acc+r3)*0.25
    spmm_csr_k<<<sp_grid, SP_BLK, 0, stream>>>(bufB, edges, offs, out, nullptr, out, 0.25f, N_NODES);
}